// Round 2
// 1680.666 us; speedup vs baseline: 1.5911x; 1.5911x over previous
//
#include <hip/hip_runtime.h>
#include <math.h>
#include <stdint.h>

#define NTOK 32768
#define KCB  4096
#define DIM  256

typedef _Float16 half4_t __attribute__((ext_vector_type(4)));
typedef _Float16 half8_t __attribute__((ext_vector_type(8)));
typedef float    floatx4 __attribute__((ext_vector_type(4)));

union H8 { half8_t v; half4_t h[2]; };

// fp32 -> (f16 hi, f16 lo) split: v = hi + lo + O(2^-24 * |v|)
__device__ __forceinline__ void split4(const float4& v, half4_t& h, half4_t& l) {
    h[0] = (_Float16)v.x; l[0] = (_Float16)(v.x - (float)h[0]);
    h[1] = (_Float16)v.y; l[1] = (_Float16)(v.y - (float)h[1]);
    h[2] = (_Float16)v.z; l[2] = (_Float16)(v.z - (float)h[2]);
    h[3] = (_Float16)v.w; l[3] = (_Float16)(v.w - (float)h[3]);
}

// ---------------------------------------------------------------------------
// K0: numpy-exact squared-norm rows for x (NTOK rows) and codebook (KCB rows).
// (unchanged — numerics-proven)
// ---------------------------------------------------------------------------
__global__ __launch_bounds__(256) void norms_kernel(
    const float* __restrict__ x, const float* __restrict__ cb,
    float* __restrict__ xnorm, float* __restrict__ cnorm) {
#pragma clang fp contract(off)
    int gid = blockIdx.x * 256 + threadIdx.x;
    int row = gid >> 4;
    int h   = (gid >> 3) & 1;
    int j   = gid & 7;

    const float* src;
    float* dst;
    if (row < NTOK) { src = x  + (size_t)row * DIM;          dst = xnorm + row; }
    else            { int r = row - NTOK;
                      src = cb + (size_t)r   * DIM;          dst = cnorm + r;   }

    const float* p = src + h * 128 + j;
    float r0 = 0.0f;
    for (int i = 0; i < 16; ++i) {
        float v = p[8 * i];
        float pr = v * v;
        r0 = r0 + pr;
    }
    __shared__ float sh[256];
    sh[threadIdx.x] = r0;
    __syncthreads();
    if ((threadIdx.x & 15) == 0) {
        const float* q = &sh[threadIdx.x];
        float left  = ((q[0] + q[1]) + (q[2] + q[3])) + ((q[4] + q[5]) + (q[6] + q[7]));
        float right = ((q[8] + q[9]) + (q[10] + q[11])) + ((q[12] + q[13]) + (q[14] + q[15]));
        *dst = left + right;
    }
}

// ---------------------------------------------------------------------------
// K1: dist[n][k] = sqrt(max((xn[n]+cn[k]) - 2*(x[n].c[k]), 0))
// MFMA f16 hi/lo split (3-term: hh + lh + hl), 128x128 tile, BK=32,
// 4 waves (2x2), 16 16x16x32 fragments per wave.
// LDS row stride 36 halfs (72B): fragment b64-pair reads conflict-free,
// staging b64 writes ~2-way.
// ---------------------------------------------------------------------------
__global__ __launch_bounds__(256) void gemm1_mfma(
    const float* __restrict__ x, const float* __restrict__ cb,
    const float* __restrict__ xnorm, const float* __restrict__ cnorm,
    float* __restrict__ dist_out) {
#pragma clang fp contract(off)
    __shared__ __align__(16) _Float16 Ah[128][36];
    __shared__ __align__(16) _Float16 Al[128][36];
    __shared__ __align__(16) _Float16 Bh[128][36];
    __shared__ __align__(16) _Float16 Bl[128][36];

    const int t    = threadIdx.x;
    const int lane = t & 63;
    const int wm   = (t >> 7) & 1;   // wave row (0..1)
    const int wn   = (t >> 6) & 1;   // wave col (0..1)
    const int g    = lane >> 4;      // k-group 0..3
    const int ci   = lane & 15;
    const int n0   = blockIdx.y * 128;
    const int k0   = blockIdx.x * 128;

    floatx4 acc[4][4];
#pragma unroll
    for (int i = 0; i < 4; ++i)
#pragma unroll
        for (int j = 0; j < 4; ++j)
            acc[i][j] = (floatx4){0.0f, 0.0f, 0.0f, 0.0f};

    for (int d0 = 0; d0 < DIM; d0 += 32) {
        // stage A (x tile 128x32) and B (cb tile 128x32), split to f16 h/l
#pragma unroll
        for (int u = 0; u < 4; ++u) {
            int i   = u * 256 + t;
            int row = i >> 3;
            int c4  = (i & 7) * 4;
            float4 va = *reinterpret_cast<const float4*>(x  + (size_t)(n0 + row) * DIM + d0 + c4);
            float4 vb = *reinterpret_cast<const float4*>(cb + (size_t)(k0 + row) * DIM + d0 + c4);
            half4_t ha, la, hb, lb;
            split4(va, ha, la);
            split4(vb, hb, lb);
            *reinterpret_cast<half4_t*>(&Ah[row][c4]) = ha;
            *reinterpret_cast<half4_t*>(&Al[row][c4]) = la;
            *reinterpret_cast<half4_t*>(&Bh[row][c4]) = hb;
            *reinterpret_cast<half4_t*>(&Bl[row][c4]) = lb;
        }
        __syncthreads();

        // A fragments: row = lane&15, k = (lane>>4)*8 + e
        H8 ah[4], al[4];
#pragma unroll
        for (int mi = 0; mi < 4; ++mi) {
            int r = wm * 64 + mi * 16 + ci;
            ah[mi].h[0] = *reinterpret_cast<const half4_t*>(&Ah[r][g * 8]);
            ah[mi].h[1] = *reinterpret_cast<const half4_t*>(&Ah[r][g * 8 + 4]);
            al[mi].h[0] = *reinterpret_cast<const half4_t*>(&Al[r][g * 8]);
            al[mi].h[1] = *reinterpret_cast<const half4_t*>(&Al[r][g * 8 + 4]);
        }
#pragma unroll
        for (int ni = 0; ni < 4; ++ni) {
            int r = wn * 64 + ni * 16 + ci;   // B col = lane&15, k contiguous
            H8 bh, bl;
            bh.h[0] = *reinterpret_cast<const half4_t*>(&Bh[r][g * 8]);
            bh.h[1] = *reinterpret_cast<const half4_t*>(&Bh[r][g * 8 + 4]);
            bl.h[0] = *reinterpret_cast<const half4_t*>(&Bl[r][g * 8]);
            bl.h[1] = *reinterpret_cast<const half4_t*>(&Bl[r][g * 8 + 4]);
#pragma unroll
            for (int mi = 0; mi < 4; ++mi) {
                acc[mi][ni] = __builtin_amdgcn_mfma_f32_16x16x32_f16(ah[mi].v, bh.v, acc[mi][ni], 0, 0, 0);
                acc[mi][ni] = __builtin_amdgcn_mfma_f32_16x16x32_f16(al[mi].v, bh.v, acc[mi][ni], 0, 0, 0);
                acc[mi][ni] = __builtin_amdgcn_mfma_f32_16x16x32_f16(ah[mi].v, bl.v, acc[mi][ni], 0, 0, 0);
            }
        }
        __syncthreads();
    }

    // epilogue: C/D layout col = lane&15, row = (lane>>4)*4 + reg
    float cn[4];
#pragma unroll
    for (int ni = 0; ni < 4; ++ni)
        cn[ni] = cnorm[k0 + wn * 64 + ni * 16 + ci];

#pragma unroll
    for (int mi = 0; mi < 4; ++mi) {
#pragma unroll
        for (int j = 0; j < 4; ++j) {
            int r = n0 + wm * 64 + mi * 16 + g * 4 + j;
            float xn = xnorm[r];
            float* orow = dist_out + (size_t)r * KCB + k0 + wn * 64 + ci;
#pragma unroll
            for (int ni = 0; ni < 4; ++ni) {
                float s  = acc[mi][ni][j];
                float sq = (xn + cn[ni]) - 2.0f * s;
                orow[ni * 16] = sqrtf(fmaxf(sq, 0.0f));
            }
        }
    }
}

// ---------------------------------------------------------------------------
// K2: per-token row pass (unchanged — numerics-proven; the gemm1 dist error
// (~1e-6) is orders below the 1e-3 recheck margin).
// ---------------------------------------------------------------------------
__global__ __launch_bounds__(256) void rowpass_kernel(
    float* __restrict__ enc,
    const float* __restrict__ noise,
    const float* __restrict__ x, const float* __restrict__ cb,
    const float* __restrict__ xnorm, const float* __restrict__ cnorm,
    float* __restrict__ idx_out) {
#pragma clang fp contract(off)
    const int n = blockIdx.x;
    const int t = threadIdx.x;
    float* row = enc + (size_t)n * KCB;
    const float* nrow = noise + (size_t)n * KCB;

    float dist[16], ee[16];
    float dmin = 3.402823466e38f;
    int   kmin = 0x7fffffff;
    float lsum = 0.0f;

#pragma unroll
    for (int u = 0; u < 4; ++u) {
        int f4 = u * 256 + t;
        float4 dv = *reinterpret_cast<const float4*>(row  + f4 * 4);
        float4 nv = *reinterpret_cast<const float4*>(nrow + f4 * 4);
        float d_[4] = {dv.x, dv.y, dv.z, dv.w};
        float n_[4] = {nv.x, nv.y, nv.z, nv.w};
#pragma unroll
        for (int j = 0; j < 4; ++j) {
            int k = f4 * 4 + j;
            float d = d_[j];
            float e = expf(n_[j] - d);
            dist[u * 4 + j] = d;
            ee[u * 4 + j] = e;
            lsum += e;
            if (d < dmin || (d == dmin && k < kmin)) { dmin = d; kmin = k; }
        }
    }

    __shared__ float sv[256];
    __shared__ int   si[256];
    __shared__ float ss[256];
    sv[t] = dmin; si[t] = kmin; ss[t] = lsum;
    __syncthreads();
    for (int s = 128; s > 0; s >>= 1) {
        if (t < s) {
            ss[t] += ss[t + s];
            float v2 = sv[t + s]; int i2 = si[t + s];
            if (v2 < sv[t] || (v2 == sv[t] && i2 < si[t])) { sv[t] = v2; si[t] = i2; }
        }
        __syncthreads();
    }
    const float rmin = sv[0];
    const float Z    = ss[0];

    const float margin = rmin + 1.0e-3f;
    float cv = 3.402823466e38f;
    int   ck = 0x7fffffff;
    const float xn = xnorm[n];
    const float* xr = x + (size_t)n * DIM;
#pragma unroll
    for (int u = 0; u < 4; ++u) {
#pragma unroll
        for (int j = 0; j < 4; ++j) {
            if (dist[u * 4 + j] <= margin) {
                int k = (u * 256 + t) * 4 + j;
                const float* cr = cb + (size_t)k * DIM;
                float acc = 0.0f;
                for (int d2 = 0; d2 < DIM; ++d2)
                    acc = __builtin_fmaf(xr[d2], cr[d2], acc);
                float sq  = (xn + cnorm[k]) - 2.0f * acc;
                float dnp = sqrtf(fmaxf(sq, 0.0f));
                if (dnp < cv || (dnp == cv && k < ck)) { cv = dnp; ck = k; }
            }
        }
    }
    __syncthreads();
    sv[t] = cv; si[t] = ck;
    __syncthreads();
    for (int s = 128; s > 0; s >>= 1) {
        if (t < s) {
            float v2 = sv[t + s]; int i2 = si[t + s];
            if (v2 < sv[t] || (v2 == sv[t] && i2 < si[t])) { sv[t] = v2; si[t] = i2; }
        }
        __syncthreads();
    }
    if (t == 0) idx_out[n] = (float)si[0];

    const float invZ = 1.0f / Z;
#pragma unroll
    for (int u = 0; u < 4; ++u) {
        int f4 = u * 256 + t;
        float4 o;
        o.x = ee[u * 4 + 0] * invZ;
        o.y = ee[u * 4 + 1] * invZ;
        o.z = ee[u * 4 + 2] * invZ;
        o.w = ee[u * 4 + 3] * invZ;
        *reinterpret_cast<float4*>(row + f4 * 4) = o;
    }
}

// ---------------------------------------------------------------------------
// K3: quantized = E (N x K) * C (K x D), MFMA f16 hi/lo split.
// 64x256 block tile (full D, E read exactly once), BK=32, 4 waves along D.
// B (cb) is contracted over its row axis -> transposed into LDS [d][k]:
// coalesced dword loads (lane = d), contiguous b64 writes per lane.
// ---------------------------------------------------------------------------
__global__ __launch_bounds__(256) void gemm2_mfma(
    const float* __restrict__ enc, const float* __restrict__ cb,
    float* __restrict__ q) {
#pragma clang fp contract(off)
    __shared__ __align__(16) _Float16 Ah[64][36];
    __shared__ __align__(16) _Float16 Al[64][36];
    __shared__ __align__(16) _Float16 Bh[256][36];
    __shared__ __align__(16) _Float16 Bl[256][36];

    const int t    = threadIdx.x;
    const int lane = t & 63;
    const int w    = t >> 6;        // wave -> D quadrant (0..3)
    const int g    = lane >> 4;
    const int ci   = lane & 15;
    const int n0   = blockIdx.x * 64;

    floatx4 acc[4][4];
#pragma unroll
    for (int i = 0; i < 4; ++i)
#pragma unroll
        for (int j = 0; j < 4; ++j)
            acc[i][j] = (floatx4){0.0f, 0.0f, 0.0f, 0.0f};

    for (int kq0 = 0; kq0 < KCB; kq0 += 32) {
        // stage A (enc tile 64x32)
#pragma unroll
        for (int u = 0; u < 2; ++u) {
            int i   = u * 256 + t;
            int row = i >> 3;
            int c4  = (i & 7) * 4;
            float4 v = *reinterpret_cast<const float4*>(enc + (size_t)(n0 + row) * KCB + kq0 + c4);
            half4_t h, l;
            split4(v, h, l);
            *reinterpret_cast<half4_t*>(&Ah[row][c4]) = h;
            *reinterpret_cast<half4_t*>(&Al[row][c4]) = l;
        }
        // stage B transposed: thread t owns column d = t; 32 coalesced dword
        // loads down the k axis, packed into contiguous b64 LDS writes.
        {
            const float* bp = cb + (size_t)kq0 * DIM + t;
#pragma unroll
            for (int j4 = 0; j4 < 8; ++j4) {
                half4_t hh, hl;
#pragma unroll
                for (int e = 0; e < 4; ++e) {
                    float v = bp[(size_t)(j4 * 4 + e) * DIM];
                    hh[e] = (_Float16)v;
                    hl[e] = (_Float16)(v - (float)hh[e]);
                }
                *reinterpret_cast<half4_t*>(&Bh[t][j4 * 4]) = hh;
                *reinterpret_cast<half4_t*>(&Bl[t][j4 * 4]) = hl;
            }
        }
        __syncthreads();

        H8 ah[4], al[4];
#pragma unroll
        for (int mi = 0; mi < 4; ++mi) {
            int r = mi * 16 + ci;
            ah[mi].h[0] = *reinterpret_cast<const half4_t*>(&Ah[r][g * 8]);
            ah[mi].h[1] = *reinterpret_cast<const half4_t*>(&Ah[r][g * 8 + 4]);
            al[mi].h[0] = *reinterpret_cast<const half4_t*>(&Al[r][g * 8]);
            al[mi].h[1] = *reinterpret_cast<const half4_t*>(&Al[r][g * 8 + 4]);
        }
#pragma unroll
        for (int ni = 0; ni < 4; ++ni) {
            int r = w * 64 + ni * 16 + ci;
            H8 bh, bl;
            bh.h[0] = *reinterpret_cast<const half4_t*>(&Bh[r][g * 8]);
            bh.h[1] = *reinterpret_cast<const half4_t*>(&Bh[r][g * 8 + 4]);
            bl.h[0] = *reinterpret_cast<const half4_t*>(&Bl[r][g * 8]);
            bl.h[1] = *reinterpret_cast<const half4_t*>(&Bl[r][g * 8 + 4]);
#pragma unroll
            for (int mi = 0; mi < 4; ++mi) {
                acc[mi][ni] = __builtin_amdgcn_mfma_f32_16x16x32_f16(ah[mi].v, bh.v, acc[mi][ni], 0, 0, 0);
                acc[mi][ni] = __builtin_amdgcn_mfma_f32_16x16x32_f16(al[mi].v, bh.v, acc[mi][ni], 0, 0, 0);
                acc[mi][ni] = __builtin_amdgcn_mfma_f32_16x16x32_f16(ah[mi].v, bl.v, acc[mi][ni], 0, 0, 0);
            }
        }
        __syncthreads();
    }

    // epilogue
#pragma unroll
    for (int mi = 0; mi < 4; ++mi) {
#pragma unroll
        for (int j = 0; j < 4; ++j) {
            int r = n0 + mi * 16 + g * 4 + j;
            float* orow = q + (size_t)r * DIM + w * 64 + ci;
#pragma unroll
            for (int ni = 0; ni < 4; ++ni)
                orow[ni * 16] = acc[mi][ni][j];
        }
    }
}

// ---------------------------------------------------------------------------
extern "C" void kernel_launch(void* const* d_in, const int* in_sizes, int n_in,
                              void* d_out, int out_size, void* d_ws, size_t ws_size,
                              hipStream_t stream) {
    const float* x     = (const float*)d_in[0];
    const float* cb    = (const float*)d_in[1];
    const float* noise = (const float*)d_in[2];

    float* out = (float*)d_out;
    float* q   = out;                                   // N*D
    float* enc = out + (size_t)NTOK * DIM;              // N*K
    float* idx = enc + (size_t)NTOK * KCB;              // N

    // scratch aliases inside d_out (no d_ws dependence):
    //   xnorm lives in the idx region (overwritten by rowpass at the end)
    //   cnorm lives in the quantized region (overwritten by gemm2 at the end)
    float* xnorm = idx;
    float* cnorm = q;

    norms_kernel<<<(NTOK + KCB) * 16 / 256, 256, 0, stream>>>(x, cb, xnorm, cnorm);

    dim3 g1(KCB / 128, NTOK / 128);
    gemm1_mfma<<<g1, 256, 0, stream>>>(x, cb, xnorm, cnorm, enc);

    rowpass_kernel<<<NTOK, 256, 0, stream>>>(enc, noise, x, cb, xnorm, cnorm, idx);

    gemm2_mfma<<<NTOK / 64, 256, 0, stream>>>(enc, cb, q);
}